// Round 8
// baseline (417.654 us; speedup 1.0000x reference)
//
#include <hip/hip_runtime.h>
#include <math.h>

typedef short s16x8 __attribute__((ext_vector_type(8)));
typedef float f32x4 __attribute__((ext_vector_type(4)));

__device__ __forceinline__ float lrelu(float x, float s) { return x > 0.0f ? x : s * x; }

// RNE f32 -> bf16 (bit-level)
__device__ __forceinline__ unsigned short f2bf(float f) {
  unsigned int u = __float_as_uint(f);
  u = (u + 0x7FFFu + ((u >> 16) & 1u)) >> 16;
  return (unsigned short)u;
}
__device__ __forceinline__ float bf2f(unsigned short h) {
  return __uint_as_float(((unsigned int)h) << 16);
}
__device__ __forceinline__ float bcastf(float v, int l) {
  return __uint_as_float((unsigned)__builtin_amdgcn_readlane((int)__float_as_uint(v), l));
}

// async global->LDS, 16B per lane; LDS dest is wave-uniform base + lane*16
__device__ __forceinline__ void gload_lds16(void* lds, const void* g) {
  __builtin_amdgcn_global_load_lds(
      (const __attribute__((address_space(1))) unsigned int*)g,
      (__attribute__((address_space(3))) unsigned int*)lds, 16, 0, 0);
}

// ======================== CSR build ========================
__global__ void deg_kernel(const int* __restrict__ dst, int* __restrict__ deg, int E) {
  int e = blockIdx.x * blockDim.x + threadIdx.x;
  if (e < E) atomicAdd(&deg[dst[e]], 1);
}

__global__ __launch_bounds__(256) void bsum_kernel(const int* __restrict__ deg,
                                                   int* __restrict__ bsum, int N) {
  int t = blockIdx.x * 256 + threadIdx.x;
  int v = (t < N) ? deg[t] : 0;
  #pragma unroll
  for (int off = 1; off < 64; off <<= 1) v += __shfl_xor(v, off, 64);
  __shared__ int ws[4];
  if ((threadIdx.x & 63) == 0) ws[threadIdx.x >> 6] = v;
  __syncthreads();
  if (threadIdx.x == 0) bsum[blockIdx.x] = ws[0] + ws[1] + ws[2] + ws[3];
}

__global__ __launch_bounds__(256) void bscan_kernel(const int* __restrict__ bsum,
                                                    int* __restrict__ boff, int nb,
                                                    int* __restrict__ rowptr_total) {
  __shared__ int s[256];
  int t = threadIdx.x;
  int v = (t < nb) ? bsum[t] : 0;
  s[t] = v;
  __syncthreads();
  for (int off = 1; off < 256; off <<= 1) {
    int u = (t >= off) ? s[t - off] : 0;
    __syncthreads();
    s[t] += u;
    __syncthreads();
  }
  if (t < nb) boff[t] = s[t] - v;
  if (t == nb - 1) *rowptr_total = s[t];
}

__global__ __launch_bounds__(256) void bwrite_kernel(const int* __restrict__ deg,
                                                     const int* __restrict__ boff,
                                                     int* __restrict__ rowptr,
                                                     int* __restrict__ cursor, int N) {
  __shared__ int s[256];
  int t = blockIdx.x * 256 + threadIdx.x;
  int v = (t < N) ? deg[t] : 0;
  s[threadIdx.x] = v;
  __syncthreads();
  for (int off = 1; off < 256; off <<= 1) {
    int u = (threadIdx.x >= off) ? s[threadIdx.x - off] : 0;
    __syncthreads();
    s[threadIdx.x] += u;
    __syncthreads();
  }
  if (t < N) {
    int ex = boff[blockIdx.x] + s[threadIdx.x] - v;
    rowptr[t] = ex;
    cursor[t] = ex;
  }
}

__global__ void fill_kernel(const int* __restrict__ src, const int* __restrict__ dst,
                            int* __restrict__ cursor, int* __restrict__ colsrc, int E) {
  int e = blockIdx.x * blockDim.x + threadIdx.x;
  if (e < E) {
    int d = dst[e];
    int pos = atomicAdd(&cursor[d], 1);
    colsrc[pos] = src[e];
  }
}

// ======================== conversions ========================
__global__ void cvt_rows_kernel(const float* __restrict__ src, unsigned short* __restrict__ dst,
                                int nrows, int prows) {
  int t = blockIdx.x * blockDim.x + threadIdx.x;
  int row = t >> 6;
  int c = (t & 63) * 4;
  if (row >= prows) return;
  float4 v = make_float4(0.f, 0.f, 0.f, 0.f);
  if (row < nrows) v = *(const float4*)&src[(size_t)row * 256 + c];
  ushort4 o;
  o.x = f2bf(v.x); o.y = f2bf(v.y); o.z = f2bf(v.z); o.w = f2bf(v.w);
  *(ushort4*)&dst[(size_t)row * 256 + c] = o;
}

// fused small setup: W1/W2 cvt (blocks 0..127), gT transpose-cvt (128..1151), munorm (1152)
__global__ __launch_bounds__(256) void wsetup_kernel(
    const float* __restrict__ W1, const float* __restrict__ W2,
    const float* __restrict__ g, const float* __restrict__ mu,
    unsigned short* __restrict__ w1b, unsigned short* __restrict__ w2b,
    unsigned short* __restrict__ gTb, float* __restrict__ nmu) {
  int b = blockIdx.x;
  int t = threadIdx.x;
  if (b < 128) {
    const float* S = (b < 64) ? W1 : W2;
    unsigned short* D = (b < 64) ? w1b : w2b;
    int bb = b & 63;
    int row = bb * 4 + (t >> 6);
    int c = (t & 63) * 4;
    float4 v = *(const float4*)&S[(size_t)row * 256 + c];
    ushort4 o;
    o.x = f2bf(v.x); o.y = f2bf(v.y); o.z = f2bf(v.z); o.w = f2bf(v.w);
    *(ushort4*)&D[(size_t)row * 256 + c] = o;
  } else if (b < 1152) {
    int idx = (b - 128) * 256 + t;          // 0..262143
    int k = idx >> 10, n = idx & 1023;
    gTb[(size_t)n * 256 + k] = f2bf(g[idx]);
  } else {
    if (t < 64) {
      int lane = t;
      for (int k = 0; k < 8; ++k) {
        float v0 = mu[k * 128 + lane];
        float v1 = mu[k * 128 + 64 + lane];
        float s = v0 * v0 + v1 * v1;
        #pragma unroll
        for (int off = 1; off < 64; off <<= 1) s += __shfl_xor(s, off, 64);
        if (lane == 0) nmu[k] = sqrtf(s);
      }
    }
  }
}

// ======================== bf16 MFMA GEMM, A-regs + nt-loop ========================
// One block per 128-row m-tile. A-fragments (all 256 k) held in registers
// (af[4][2][2], staged once through LDS). Loop nt over NT 128-col tiles of B;
// B double-buffered in LDS (2 x 16KB), stage-next issued before compute, one
// __syncthreads per (nt,kb) step (drains vmcnt -> staged buffer valid next step).
// B total is small (W: 128KB, gT: 512KB) -> L2-resident; A read ONCE from HBM.
// LDS 16B-chunk XOR-swizzle via pre-swizzled global src (rule 21), both sides.
// EPI=0: store C bf16; AH==2: nt==head alpha-dot store; AH==1: atomicAdd partials.
// EPI=1: fused cosine epilogue per nt (nt == kchunk).
template<int EPI, int AH, int NT>
__global__ __launch_bounds__(256, 2) void gemm_bf16(
    const unsigned short* __restrict__ A, const unsigned short* __restrict__ B,
    unsigned short* __restrict__ Cb,
    const float* __restrict__ avs, const float* __restrict__ avd,
    float* __restrict__ asrcO, float* __restrict__ adstO,
    const float* __restrict__ mu, const float* __restrict__ nmu,
    float* __restrict__ outcos, int M)
{
  __shared__ unsigned short Bs[2][128 * 64];
  const int t = threadIdx.x;
  const int w = t >> 6;
  const int l = t & 63;
  const int m0 = blockIdx.x * 128;
  const int rl = l & 15;
  const int kc = l >> 4;                 // 0..3
  const int srow = l >> 3;               // 0..7
  const int gchk = (l & 7) ^ srow;       // pre-swizzled global 16B-chunk

  const unsigned char* Ab = (const unsigned char*)A;
  const unsigned char* Bb = (const unsigned char*)B;

  // ---- prologue: A -> registers (staged via Bs, parity alternates) ----
  s16x8 af[4][2][2];
  #pragma unroll
  for (int kb = 0; kb < 4; ++kb) {
    unsigned char* buf = (unsigned char*)&Bs[kb & 1][0];
    #pragma unroll
    for (int i = 0; i < 4; ++i) {
      int seg = w * 4 + i;
      int row = seg * 8 + srow;
      gload_lds16(buf + seg * 1024,
                  Ab + (size_t)(m0 + row) * 512 + kb * 128 + gchk * 16);
    }
    __syncthreads();                      // drains vmcnt: staged data valid
    #pragma unroll
    for (int ks = 0; ks < 2; ++ks)
      #pragma unroll
      for (int mf = 0; mf < 2; ++mf) {
        int r = w * 32 + mf * 16 + rl;
        int slot = (ks * 4 + kc) ^ (r & 7);
        af[kb][ks][mf] = *(const s16x8*)&Bs[kb & 1][r * 64 + slot * 8];
      }
    __syncthreads();                      // reads drained before buffer reuse
  }

  // ---- initial B stage (nt=0, kb=0) -> buf0 ----
  {
    unsigned char* buf = (unsigned char*)&Bs[0][0];
    #pragma unroll
    for (int i = 0; i < 4; ++i) {
      int seg = w * 4 + i;
      int row = seg * 8 + srow;
      gload_lds16(buf + seg * 1024,
                  Bb + (size_t)row * 512 + gchk * 16);
    }
  }
  __syncthreads();

  for (int nt = 0; nt < NT; ++nt) {
    f32x4 acc[2][8];
    #pragma unroll
    for (int i = 0; i < 2; ++i)
      #pragma unroll
      for (int j = 0; j < 8; ++j) acc[i][j] = (f32x4){0.f, 0.f, 0.f, 0.f};

    #pragma unroll
    for (int kb = 0; kb < 4; ++kb) {
      // issue next-tile stage into the other buffer (overlaps with compute below)
      bool last = (nt == NT - 1) && (kb == 3);
      if (!last) {
        int nnt = nt + (kb == 3);
        int nkb = (kb + 1) & 3;
        unsigned char* buf = (unsigned char*)&Bs[(kb + 1) & 1][0];
        #pragma unroll
        for (int i = 0; i < 4; ++i) {
          int seg = w * 4 + i;
          int row = seg * 8 + srow;
          gload_lds16(buf + seg * 1024,
                      Bb + (size_t)(nnt * 128 + row) * 512 + nkb * 128 + gchk * 16);
        }
      }
      // compute on current buffer (staged last step, validated by the syncthreads)
      #pragma unroll
      for (int ks = 0; ks < 2; ++ks) {
        s16x8 bfr[8];
        #pragma unroll
        for (int nf = 0; nf < 8; ++nf) {
          int r = nf * 16 + rl;
          int slot = (ks * 4 + kc) ^ (r & 7);
          bfr[nf] = *(const s16x8*)&Bs[kb & 1][r * 64 + slot * 8];
        }
        #pragma unroll
        for (int mf = 0; mf < 2; ++mf)
          #pragma unroll
          for (int nf = 0; nf < 8; ++nf)
            acc[mf][nf] = __builtin_amdgcn_mfma_f32_16x16x32_bf16(af[kb][ks][mf], bfr[nf], acc[mf][nf], 0, 0, 0);
      }
      __syncthreads();   // reads done (all waves) + next stage drained (vmcnt0)
    }

    // ---- epilogue for this nt ----
    if (EPI == 0) {
      // C/D layout: col = lane&15, row = (lane>>4)*4 + reg
      int n0 = nt * 128;
      #pragma unroll
      for (int mf = 0; mf < 2; ++mf)
        #pragma unroll
        for (int nf = 0; nf < 8; ++nf)
          #pragma unroll
          for (int j = 0; j < 4; ++j) {
            int r = m0 + w * 32 + mf * 16 + (l >> 4) * 4 + j;
            int c = n0 + nf * 16 + rl;
            Cb[(size_t)r * 256 + c] = f2bf(acc[mf][nf][j]);
          }
      if (AH > 0) {
        float avS[8], avD[8];
        #pragma unroll
        for (int nf = 0; nf < 8; ++nf) {
          avS[nf] = avs[n0 + nf * 16 + rl];
          avD[nf] = avd[n0 + nf * 16 + rl];
        }
        #pragma unroll
        for (int mf = 0; mf < 2; ++mf)
          #pragma unroll
          for (int j = 0; j < 4; ++j) {
            float ds = 0.f, dd = 0.f;
            #pragma unroll
            for (int nf = 0; nf < 8; ++nf) {
              float o = acc[mf][nf][j];
              ds = fmaf(o, avS[nf], ds);
              dd = fmaf(o, avD[nf], dd);
            }
            #pragma unroll
            for (int off = 1; off < 16; off <<= 1) {
              ds += __shfl_xor(ds, off, 64);
              dd += __shfl_xor(dd, off, 64);
            }
            if (rl == 0) {
              int r = m0 + w * 32 + mf * 16 + (l >> 4) * 4 + j;
              if (r < M) {
                if (AH == 2) {
                  asrcO[(size_t)r * 2 + nt] = ds;
                  adstO[(size_t)r * 2 + nt] = dd;
                } else {
                  atomicAdd(&asrcO[r], ds);
                  atomicAdd(&adstO[r], dd);
                }
              }
            }
          }
      }
    } else {
      float nm = nmu[nt];
      float mv[8];
      #pragma unroll
      for (int nf = 0; nf < 8; ++nf) mv[nf] = mu[nt * 128 + nf * 16 + rl];
      #pragma unroll
      for (int mf = 0; mf < 2; ++mf)
        #pragma unroll
        for (int j = 0; j < 4; ++j) {
          float num = 0.f, ss = 0.f;
          #pragma unroll
          for (int nf = 0; nf < 8; ++nf) {
            float o = acc[mf][nf][j];
            num = fmaf(o, mv[nf], num);
            ss  = fmaf(o, o, ss);
          }
          #pragma unroll
          for (int off = 1; off < 16; off <<= 1) {
            num += __shfl_xor(num, off, 64);
            ss  += __shfl_xor(ss, off, 64);
          }
          if (rl == 0) {
            int r = m0 + w * 32 + mf * 16 + (l >> 4) * 4 + j;
            if (r < M) outcos[(size_t)r * 8 + nt] = num / fmaxf(sqrtf(ss) * nm, 1e-8f);
          }
        }
    }
  }
}

// ======================== GAT aggregation ========================
// One wave per node; lane owns 4 feature cols. Lane-parallel chunked online
// softmax (64 edges/chunk). Gather: one edge per step across 64 lanes (8B/lane),
// (src, alpha) broadcast via v_readlane (SGPR base loads), unrolled x8.
template<int H, bool OUT_LRELU>
__global__ __launch_bounds__(256) void agg_kernel(
    const unsigned short* __restrict__ hin, const float* __restrict__ asrc,
    const float* __restrict__ adst, const int* __restrict__ rowptr,
    const int* __restrict__ colsrc, const float* __restrict__ bias,
    unsigned short* __restrict__ outp, int N)
{
  int wid  = threadIdx.x >> 6;
  int lane = threadIdx.x & 63;
  int n = blockIdx.x * 4 + wid;
  if (n >= N) return;
  const int head = (H == 2) ? (lane >> 5) : 0;

  int beg = rowptr[n], end = rowptr[n + 1];

  float ad0 = adst[(size_t)n * H + 0];
  float ad1 = (H == 2) ? adst[(size_t)n * 2 + 1] : 0.f;
  float m0 = lrelu(asrc[(size_t)n * H + 0] + ad0, 0.2f);
  float m1 = (H == 2) ? lrelu(asrc[(size_t)n * 2 + 1] + ad1, 0.2f) : 0.f;
  float s0 = 1.f, s1 = 1.f;

  float acc[4];
  {
    ushort4 hv = *(const ushort4*)&hin[(size_t)n * 256 + lane * 4];
    acc[0] = bf2f(hv.x); acc[1] = bf2f(hv.y);
    acc[2] = bf2f(hv.z); acc[3] = bf2f(hv.w);
  }

  for (int cbeg = beg; cbeg < end; cbeg += 64) {
    int cnt = end - cbeg; if (cnt > 64) cnt = 64;
    int src_i = 0;
    float e0 = -1e30f, e1 = -1e30f;
    if (lane < cnt) {
      src_i = colsrc[cbeg + lane];
      if (H == 2) {
        float2 av = *(const float2*)&asrc[(size_t)src_i * 2];
        e0 = lrelu(av.x + ad0, 0.2f);
        e1 = lrelu(av.y + ad1, 0.2f);
      } else {
        e0 = lrelu(asrc[src_i] + ad0, 0.2f);
      }
    }
    float c0 = e0, c1 = e1;
    #pragma unroll
    for (int off = 32; off >= 1; off >>= 1) {
      c0 = fmaxf(c0, __shfl_xor(c0, off, 64));
      if (H == 2) c1 = fmaxf(c1, __shfl_xor(c1, off, 64));
    }
    float nm0 = fmaxf(m0, c0);
    float r0 = __expf(m0 - nm0); m0 = nm0;
    float r1 = 1.f;
    if (H == 2) { float nm1 = fmaxf(m1, c1); r1 = __expf(m1 - nm1); m1 = nm1; }
    s0 *= r0; if (H == 2) s1 *= r1;
    float rh = (H == 2 && head) ? r1 : r0;
    #pragma unroll
    for (int k = 0; k < 4; ++k) acc[k] *= rh;
    float p0 = (lane < cnt) ? __expf(e0 - m0) : 0.f;
    float p1 = (H == 2 && lane < cnt) ? __expf(e1 - m1) : 0.f;
    float t0 = p0, t1 = p1;
    #pragma unroll
    for (int off = 32; off >= 1; off >>= 1) {
      t0 += __shfl_xor(t0, off, 64);
      if (H == 2) t1 += __shfl_xor(t1, off, 64);
    }
    s0 += t0; if (H == 2) s1 += t1;

    // gather: 8 edges in flight; padded edges have src=0, p=0 (harmless)
    int ne8 = (cnt + 7) & ~7;
    for (int e = 0; e < ne8; e += 8) {
      ushort4 v[8]; float aw[8];
      #pragma unroll
      for (int u = 0; u < 8; ++u) {
        int sidx = __builtin_amdgcn_readlane(src_i, e + u);
        float a0 = bcastf(p0, e + u);
        if (H == 2) {
          float a1 = bcastf(p1, e + u);
          aw[u] = head ? a1 : a0;
        } else {
          aw[u] = a0;
        }
        v[u] = *(const ushort4*)&hin[(size_t)sidx * 256 + lane * 4];
      }
      #pragma unroll
      for (int u = 0; u < 8; ++u) {
        acc[0] = fmaf(bf2f(v[u].x), aw[u], acc[0]);
        acc[1] = fmaf(bf2f(v[u].y), aw[u], acc[1]);
        acc[2] = fmaf(bf2f(v[u].z), aw[u], acc[2]);
        acc[3] = fmaf(bf2f(v[u].w), aw[u], acc[3]);
      }
    }
  }

  float sh = (H == 2 && head) ? s1 : s0;
  float inv = 1.0f / sh;
  float4 bv = *(const float4*)&bias[lane * 4];
  float o0 = acc[0] * inv + bv.x, o1 = acc[1] * inv + bv.y;
  float o2 = acc[2] * inv + bv.z, o3 = acc[3] * inv + bv.w;
  if (OUT_LRELU) {
    o0 = lrelu(o0, 0.01f); o1 = lrelu(o1, 0.01f);
    o2 = lrelu(o2, 0.01f); o3 = lrelu(o3, 0.01f);
  }
  ushort4 o;
  o.x = f2bf(o0); o.y = f2bf(o1); o.z = f2bf(o2); o.w = f2bf(o3);
  *(ushort4*)&outp[(size_t)n * 256 + lane * 4] = o;
}

// ======================== launch ========================
extern "C" void kernel_launch(void* const* d_in, const int* in_sizes, int n_in,
                              void* d_out, int out_size, void* d_ws, size_t ws_size,
                              hipStream_t stream) {
  const float* x      = (const float*)d_in[0];
  const int*   ei     = (const int*)  d_in[1];
  const float* W1     = (const float*)d_in[2];
  const float* a_src1 = (const float*)d_in[3];
  const float* a_dst1 = (const float*)d_in[4];
  const float* b1     = (const float*)d_in[5];
  const float* W2     = (const float*)d_in[6];
  const float* a_src2 = (const float*)d_in[7];
  const float* a_dst2 = (const float*)d_in[8];
  const float* b2     = (const float*)d_in[9];
  const float* g      = (const float*)d_in[10];
  const float* mu     = (const float*)d_in[11];

  const int N  = in_sizes[0] / 256;            // 50000
  const int E  = in_sizes[1] / 2;              // 800000
  const int Mp = ((N + 127) / 128) * 128;      // 50048
  const int nb = (N + 255) / 256;              // 196 scan blocks
  const int* src = ei;
  const int* dst = ei + E;

  // ---- workspace layout ----
  unsigned short* us = (unsigned short*)d_ws;
  size_t off = 0;
  unsigned short* xb  = us + off; off += (size_t)Mp * 256;
  unsigned short* h1b = us + off; off += (size_t)Mp * 256;
  unsigned short* o1b = us + off; off += (size_t)Mp * 256;
  unsigned short* h2b = us + off; off += (size_t)Mp * 256;
  unsigned short* o2b = xb;                                  // alias
  float* f = (float*)(us + off);
  size_t fo = 0;
  float* asrc1 = f + fo; fo += (size_t)N * 2;
  float* adst1 = f + fo; fo += (size_t)N * 2;
  float* asrc2 = f + fo; fo += N;
  float* adst2 = f + fo; fo += N;
  float* nmu   = f + fo; fo += 8;
  int* deg    = (int*)(f + fo);
  int* rowptr = deg + N;
  int* cursor = rowptr + N + 1;
  int* colsrc = cursor + N;
  int* bsum   = colsrc + E;
  int* boff   = bsum + 256;
  unsigned short* w1b = (unsigned short*)(boff + 256);
  unsigned short* w2b = w1b + 256 * 256;
  unsigned short* gTb = w2b + 256 * 256;

  // ---- CSR build ----
  hipMemsetAsync(deg, 0, (size_t)N * sizeof(int), stream);
  hipMemsetAsync(asrc2, 0, (size_t)N * 2 * sizeof(float), stream);
  deg_kernel<<<(E + 255) / 256, 256, 0, stream>>>(dst, deg, E);
  bsum_kernel<<<nb, 256, 0, stream>>>(deg, bsum, N);
  bscan_kernel<<<1, 256, 0, stream>>>(bsum, boff, nb, rowptr + N);
  bwrite_kernel<<<nb, 256, 0, stream>>>(deg, boff, rowptr, cursor, N);
  fill_kernel<<<(E + 255) / 256, 256, 0, stream>>>(src, dst, cursor, colsrc, E);

  // ---- conversions ----
  cvt_rows_kernel<<<Mp / 4, 256, 0, stream>>>(x, xb, N, Mp);
  wsetup_kernel<<<1153, 256, 0, stream>>>(W1, W2, g, mu, w1b, w2b, gTb, nmu);

  const int gm = Mp / 128;   // 391

  // ---- layer 1 (alpha fused: nt == head) ----
  gemm_bf16<0, 2, 2><<<gm, 256, 0, stream>>>(xb, w1b, h1b,
      a_src1, a_dst1, asrc1, adst1, nullptr, nullptr, nullptr, N);
  agg_kernel<2, true><<<(N + 3) / 4, 256, 0, stream>>>(h1b, asrc1, adst1, rowptr, colsrc, b1, o1b, N);

  // ---- layer 2 (alpha partials via atomicAdd) ----
  gemm_bf16<0, 1, 2><<<gm, 256, 0, stream>>>(o1b, w2b, h2b,
      a_src2, a_dst2, asrc2, adst2, nullptr, nullptr, nullptr, N);
  agg_kernel<1, false><<<(N + 3) / 4, 256, 0, stream>>>(h2b, asrc2, adst2, rowptr, colsrc, b2, o2b, N);

  // ---- projection + fused cosine (nt == kchunk) ----
  gemm_bf16<1, 0, 8><<<gm, 256, 0, stream>>>(o2b, gTb, nullptr,
      nullptr, nullptr, nullptr, nullptr, mu, nmu, (float*)d_out, N);
}

// Round 9
// 410.836 us; speedup vs baseline: 1.0166x; 1.0166x over previous
//
#include <hip/hip_runtime.h>
#include <math.h>

typedef _Float16 f16x8 __attribute__((ext_vector_type(8)));
typedef _Float16 h2 __attribute__((ext_vector_type(2)));
typedef float f32x4 __attribute__((ext_vector_type(4)));

__device__ __forceinline__ float lrelu(float x, float s) { return x > 0.0f ? x : s * x; }

// f32 -> f16 (RNE) stored as ushort
__device__ __forceinline__ unsigned short f2h(float f) {
  _Float16 h = (_Float16)f;
  return __builtin_bit_cast(unsigned short, h);
}
__device__ __forceinline__ float bcastf(float v, int l) {
  return __uint_as_float((unsigned)__builtin_amdgcn_readlane((int)__float_as_uint(v), l));
}

// async global->LDS, 16B per lane; LDS dest is wave-uniform base + lane*16
__device__ __forceinline__ void gload_lds16(void* lds, const void* g) {
  __builtin_amdgcn_global_load_lds(
      (const __attribute__((address_space(1))) unsigned int*)g,
      (__attribute__((address_space(3))) unsigned int*)lds, 16, 0, 0);
}

// ======================== CSR build ========================
__global__ void deg_kernel(const int* __restrict__ dst, int* __restrict__ deg, int E) {
  int e = blockIdx.x * blockDim.x + threadIdx.x;
  if (e < E) atomicAdd(&deg[dst[e]], 1);
}

__global__ __launch_bounds__(256) void bsum_kernel(const int* __restrict__ deg,
                                                   int* __restrict__ bsum, int N) {
  int t = blockIdx.x * 256 + threadIdx.x;
  int v = (t < N) ? deg[t] : 0;
  #pragma unroll
  for (int off = 1; off < 64; off <<= 1) v += __shfl_xor(v, off, 64);
  __shared__ int ws[4];
  if ((threadIdx.x & 63) == 0) ws[threadIdx.x >> 6] = v;
  __syncthreads();
  if (threadIdx.x == 0) bsum[blockIdx.x] = ws[0] + ws[1] + ws[2] + ws[3];
}

__global__ __launch_bounds__(256) void bscan_kernel(const int* __restrict__ bsum,
                                                    int* __restrict__ boff, int nb,
                                                    int* __restrict__ rowptr_total) {
  __shared__ int s[256];
  int t = threadIdx.x;
  int v = (t < nb) ? bsum[t] : 0;
  s[t] = v;
  __syncthreads();
  for (int off = 1; off < 256; off <<= 1) {
    int u = (t >= off) ? s[t - off] : 0;
    __syncthreads();
    s[t] += u;
    __syncthreads();
  }
  if (t < nb) boff[t] = s[t] - v;
  if (t == nb - 1) *rowptr_total = s[t];
}

__global__ __launch_bounds__(256) void bwrite_kernel(const int* __restrict__ deg,
                                                     const int* __restrict__ boff,
                                                     int* __restrict__ rowptr,
                                                     int* __restrict__ cursor, int N) {
  __shared__ int s[256];
  int t = blockIdx.x * 256 + threadIdx.x;
  int v = (t < N) ? deg[t] : 0;
  s[threadIdx.x] = v;
  __syncthreads();
  for (int off = 1; off < 256; off <<= 1) {
    int u = (threadIdx.x >= off) ? s[threadIdx.x - off] : 0;
    __syncthreads();
    s[threadIdx.x] += u;
    __syncthreads();
  }
  if (t < N) {
    int ex = boff[blockIdx.x] + s[threadIdx.x] - v;
    rowptr[t] = ex;
    cursor[t] = ex;
  }
}

__global__ void fill_kernel(const int* __restrict__ src, const int* __restrict__ dst,
                            int* __restrict__ cursor, int* __restrict__ colsrc, int E) {
  int e = blockIdx.x * blockDim.x + threadIdx.x;
  if (e < E) {
    int d = dst[e];
    int pos = atomicAdd(&cursor[d], 1);
    colsrc[pos] = src[e];
  }
}

// ======================== conversions ========================
__global__ void cvt_rows_kernel(const float* __restrict__ src, unsigned short* __restrict__ dst,
                                int nrows, int prows) {
  int t = blockIdx.x * blockDim.x + threadIdx.x;
  int row = t >> 6;
  int c = (t & 63) * 4;
  if (row >= prows) return;
  float4 v = make_float4(0.f, 0.f, 0.f, 0.f);
  if (row < nrows) v = *(const float4*)&src[(size_t)row * 256 + c];
  ushort4 o;
  o.x = f2h(v.x); o.y = f2h(v.y); o.z = f2h(v.z); o.w = f2h(v.w);
  *(ushort4*)&dst[(size_t)row * 256 + c] = o;
}

// fused small setup: W1/W2 cvt (blocks 0..127), gT transpose-cvt (128..1151), munorm (1152)
__global__ __launch_bounds__(256) void wsetup_kernel(
    const float* __restrict__ W1, const float* __restrict__ W2,
    const float* __restrict__ g, const float* __restrict__ mu,
    unsigned short* __restrict__ w1b, unsigned short* __restrict__ w2b,
    unsigned short* __restrict__ gTb, float* __restrict__ nmu) {
  int b = blockIdx.x;
  int t = threadIdx.x;
  if (b < 128) {
    const float* S = (b < 64) ? W1 : W2;
    unsigned short* D = (b < 64) ? w1b : w2b;
    int bb = b & 63;
    int row = bb * 4 + (t >> 6);
    int c = (t & 63) * 4;
    float4 v = *(const float4*)&S[(size_t)row * 256 + c];
    ushort4 o;
    o.x = f2h(v.x); o.y = f2h(v.y); o.z = f2h(v.z); o.w = f2h(v.w);
    *(ushort4*)&D[(size_t)row * 256 + c] = o;
  } else if (b < 1152) {
    int idx = (b - 128) * 256 + t;          // 0..262143
    int k = idx >> 10, n = idx & 1023;
    gTb[(size_t)n * 256 + k] = f2h(g[idx]);
  } else {
    if (t < 64) {
      int lane = t;
      for (int k = 0; k < 8; ++k) {
        float v0 = mu[k * 128 + lane];
        float v1 = mu[k * 128 + 64 + lane];
        float s = v0 * v0 + v1 * v1;
        #pragma unroll
        for (int off = 1; off < 64; off <<= 1) s += __shfl_xor(s, off, 64);
        if (lane == 0) nmu[k] = sqrtf(s);
      }
    }
  }
}

// ======================== f16 MFMA GEMM, A-regs + nt-loop ========================
// One block per 128-row m-tile. A-fragments (all 256 k) in registers (staged via LDS).
// nt-loop over NT 128-col tiles of B; B double-buffered in LDS, stage-next issued
// before compute, one __syncthreads per (nt,kb) step. B L2-resident; A read once.
// LDS 16B-chunk XOR-swizzle via pre-swizzled global src (rule 21), both sides.
// EPI=0: store C f16; AH==2: nt==head alpha-dot store; AH==1: atomicAdd partials.
// EPI=1: fused cosine epilogue per nt (nt == kchunk).
template<int EPI, int AH, int NT>
__global__ __launch_bounds__(256, 2) void gemm_f16(
    const unsigned short* __restrict__ A, const unsigned short* __restrict__ B,
    unsigned short* __restrict__ Cb,
    const float* __restrict__ avs, const float* __restrict__ avd,
    float* __restrict__ asrcO, float* __restrict__ adstO,
    const float* __restrict__ mu, const float* __restrict__ nmu,
    float* __restrict__ outcos, int M)
{
  __shared__ unsigned short Bs[2][128 * 64];
  const int t = threadIdx.x;
  const int w = t >> 6;
  const int l = t & 63;
  const int m0 = blockIdx.x * 128;
  const int rl = l & 15;
  const int kc = l >> 4;                 // 0..3
  const int srow = l >> 3;               // 0..7
  const int gchk = (l & 7) ^ srow;       // pre-swizzled global 16B-chunk

  const unsigned char* Ab = (const unsigned char*)A;
  const unsigned char* Bb = (const unsigned char*)B;

  // ---- prologue: A -> registers (staged via Bs, parity alternates) ----
  f16x8 af[4][2][2];
  #pragma unroll
  for (int kb = 0; kb < 4; ++kb) {
    unsigned char* buf = (unsigned char*)&Bs[kb & 1][0];
    #pragma unroll
    for (int i = 0; i < 4; ++i) {
      int seg = w * 4 + i;
      int row = seg * 8 + srow;
      gload_lds16(buf + seg * 1024,
                  Ab + (size_t)(m0 + row) * 512 + kb * 128 + gchk * 16);
    }
    __syncthreads();
    #pragma unroll
    for (int ks = 0; ks < 2; ++ks)
      #pragma unroll
      for (int mf = 0; mf < 2; ++mf) {
        int r = w * 32 + mf * 16 + rl;
        int slot = (ks * 4 + kc) ^ (r & 7);
        af[kb][ks][mf] = *(const f16x8*)&Bs[kb & 1][r * 64 + slot * 8];
      }
    __syncthreads();
  }

  // ---- initial B stage (nt=0, kb=0) -> buf0 ----
  {
    unsigned char* buf = (unsigned char*)&Bs[0][0];
    #pragma unroll
    for (int i = 0; i < 4; ++i) {
      int seg = w * 4 + i;
      int row = seg * 8 + srow;
      gload_lds16(buf + seg * 1024,
                  Bb + (size_t)row * 512 + gchk * 16);
    }
  }
  __syncthreads();

  for (int nt = 0; nt < NT; ++nt) {
    f32x4 acc[2][8];
    #pragma unroll
    for (int i = 0; i < 2; ++i)
      #pragma unroll
      for (int j = 0; j < 8; ++j) acc[i][j] = (f32x4){0.f, 0.f, 0.f, 0.f};

    #pragma unroll
    for (int kb = 0; kb < 4; ++kb) {
      bool last = (nt == NT - 1) && (kb == 3);
      if (!last) {
        int nnt = nt + (kb == 3);
        int nkb = (kb + 1) & 3;
        unsigned char* buf = (unsigned char*)&Bs[(kb + 1) & 1][0];
        #pragma unroll
        for (int i = 0; i < 4; ++i) {
          int seg = w * 4 + i;
          int row = seg * 8 + srow;
          gload_lds16(buf + seg * 1024,
                      Bb + (size_t)(nnt * 128 + row) * 512 + nkb * 128 + gchk * 16);
        }
      }
      #pragma unroll
      for (int ks = 0; ks < 2; ++ks) {
        f16x8 bfr[8];
        #pragma unroll
        for (int nf = 0; nf < 8; ++nf) {
          int r = nf * 16 + rl;
          int slot = (ks * 4 + kc) ^ (r & 7);
          bfr[nf] = *(const f16x8*)&Bs[kb & 1][r * 64 + slot * 8];
        }
        #pragma unroll
        for (int mf = 0; mf < 2; ++mf)
          #pragma unroll
          for (int nf = 0; nf < 8; ++nf)
            acc[mf][nf] = __builtin_amdgcn_mfma_f32_16x16x32_f16(af[kb][ks][mf], bfr[nf], acc[mf][nf], 0, 0, 0);
      }
      __syncthreads();
    }

    // ---- epilogue for this nt ----
    if (EPI == 0) {
      // C/D layout: col = lane&15, row = (lane>>4)*4 + reg
      int n0 = nt * 128;
      #pragma unroll
      for (int mf = 0; mf < 2; ++mf)
        #pragma unroll
        for (int nf = 0; nf < 8; ++nf)
          #pragma unroll
          for (int j = 0; j < 4; ++j) {
            int r = m0 + w * 32 + mf * 16 + (l >> 4) * 4 + j;
            int c = n0 + nf * 16 + rl;
            Cb[(size_t)r * 256 + c] = f2h(acc[mf][nf][j]);
          }
      if (AH > 0) {
        float avS[8], avD[8];
        #pragma unroll
        for (int nf = 0; nf < 8; ++nf) {
          avS[nf] = avs[n0 + nf * 16 + rl];
          avD[nf] = avd[n0 + nf * 16 + rl];
        }
        #pragma unroll
        for (int mf = 0; mf < 2; ++mf)
          #pragma unroll
          for (int j = 0; j < 4; ++j) {
            float ds = 0.f, dd = 0.f;
            #pragma unroll
            for (int nf = 0; nf < 8; ++nf) {
              float o = acc[mf][nf][j];
              ds = fmaf(o, avS[nf], ds);
              dd = fmaf(o, avD[nf], dd);
            }
            #pragma unroll
            for (int off = 1; off < 16; off <<= 1) {
              ds += __shfl_xor(ds, off, 64);
              dd += __shfl_xor(dd, off, 64);
            }
            if (rl == 0) {
              int r = m0 + w * 32 + mf * 16 + (l >> 4) * 4 + j;
              if (r < M) {
                if (AH == 2) {
                  asrcO[(size_t)r * 2 + nt] = ds;
                  adstO[(size_t)r * 2 + nt] = dd;
                } else {
                  atomicAdd(&asrcO[r], ds);
                  atomicAdd(&adstO[r], dd);
                }
              }
            }
          }
      }
    } else {
      float nm = nmu[nt];
      float mv[8];
      #pragma unroll
      for (int nf = 0; nf < 8; ++nf) mv[nf] = mu[nt * 128 + nf * 16 + rl];
      #pragma unroll
      for (int mf = 0; mf < 2; ++mf)
        #pragma unroll
        for (int j = 0; j < 4; ++j) {
          float num = 0.f, ss = 0.f;
          #pragma unroll
          for (int nf = 0; nf < 8; ++nf) {
            float o = acc[mf][nf][j];
            num = fmaf(o, mv[nf], num);
            ss  = fmaf(o, o, ss);
          }
          #pragma unroll
          for (int off = 1; off < 16; off <<= 1) {
            num += __shfl_xor(num, off, 64);
            ss  += __shfl_xor(ss, off, 64);
          }
          if (rl == 0) {
            int r = m0 + w * 32 + mf * 16 + (l >> 4) * 4 + j;
            if (r < M) outcos[(size_t)r * 8 + nt] = num / fmaxf(sqrtf(ss) * nm, 1e-8f);
          }
        }
    }
  }
}

// ======================== GAT aggregation (f16, packed-fma) ========================
// One wave per node; lane owns 4 feature cols (2 x h2). Lane-parallel chunked
// online softmax (64 edges/chunk) with per-lane PACKED f16 weights (p0,p1).
// Gather: one edge per step across 64 lanes (8B/lane); broadcast = 1 readlane(src)
// + 1 readlane(packed w) + 1 v_perm head-splat; accumulate = 2 v_pk_fma_f16.
// Unrolled x4 => 4 row-loads in flight; padded edges have src=0, w=0 (harmless).
template<int H, bool OUT_LRELU>
__global__ __launch_bounds__(256) void agg_kernel(
    const unsigned short* __restrict__ hin, const float* __restrict__ asrc,
    const float* __restrict__ adst, const int* __restrict__ rowptr,
    const int* __restrict__ colsrc, const float* __restrict__ bias,
    unsigned short* __restrict__ outp, int N)
{
  int wid  = threadIdx.x >> 6;
  int lane = threadIdx.x & 63;
  int n = blockIdx.x * 4 + wid;
  if (n >= N) return;
  const int head = (H == 2) ? (lane >> 5) : 0;
  const unsigned psel = head ? 0x03020302u : 0x01000100u;   // v_perm: splat hi/lo f16

  int beg = rowptr[n], end = rowptr[n + 1];

  float ad0 = adst[(size_t)n * H + 0];
  float ad1 = (H == 2) ? adst[(size_t)n * 2 + 1] : 0.f;
  float m0 = lrelu(asrc[(size_t)n * H + 0] + ad0, 0.2f);    // self-loop logit
  float m1 = (H == 2) ? lrelu(asrc[(size_t)n * 2 + 1] + ad1, 0.2f) : 0.f;
  float s0 = 1.f, s1 = 1.f;

  h2 acc0, acc1;
  {
    uint2 hv = *(const uint2*)&hin[(size_t)n * 256 + lane * 4];
    acc0 = __builtin_bit_cast(h2, hv.x);
    acc1 = __builtin_bit_cast(h2, hv.y);
  }

  for (int cbeg = beg; cbeg < end; cbeg += 64) {
    int cnt = end - cbeg; if (cnt > 64) cnt = 64;
    int src_i = 0;
    float e0 = -1e30f, e1 = -1e30f;
    if (lane < cnt) {
      src_i = colsrc[cbeg + lane];
      if (H == 2) {
        float2 av = *(const float2*)&asrc[(size_t)src_i * 2];
        e0 = lrelu(av.x + ad0, 0.2f);
        e1 = lrelu(av.y + ad1, 0.2f);
      } else {
        e0 = lrelu(asrc[src_i] + ad0, 0.2f);
      }
    }
    // chunk max
    float c0 = e0, c1 = e1;
    #pragma unroll
    for (int off = 32; off >= 1; off >>= 1) {
      c0 = fmaxf(c0, __shfl_xor(c0, off, 64));
      if (H == 2) c1 = fmaxf(c1, __shfl_xor(c1, off, 64));
    }
    float nm0 = fmaxf(m0, c0);
    float r0 = __expf(m0 - nm0); m0 = nm0;
    float r1 = 1.f;
    if (H == 2) { float nm1 = fmaxf(m1, c1); r1 = __expf(m1 - nm1); m1 = nm1; }
    s0 *= r0; if (H == 2) s1 *= r1;
    float rh = (H == 2 && head) ? r1 : r0;
    {
      _Float16 rhh = (_Float16)rh;
      h2 rh2 = {rhh, rhh};
      acc0 *= rh2; acc1 *= rh2;
    }
    // per-edge p (0 for invalid lanes), packed f16 (p0,p1)
    float p0 = (lane < cnt) ? __expf(e0 - m0) : 0.f;
    float p1 = (H == 2 && lane < cnt) ? __expf(e1 - m1) : 0.f;
    unsigned pk;
    {
      _Float16 q0 = (_Float16)p0;
      _Float16 q1 = (H == 2) ? (_Float16)p1 : q0;
      h2 pr = {q0, q1};
      pk = __builtin_bit_cast(unsigned, pr);
    }
    float t0 = p0, t1 = p1;
    #pragma unroll
    for (int off = 32; off >= 1; off >>= 1) {
      t0 += __shfl_xor(t0, off, 64);
      if (H == 2) t1 += __shfl_xor(t1, off, 64);
    }
    s0 += t0; if (H == 2) s1 += t1;

    // gather: 4 edges in flight
    int ne4 = (cnt + 3) & ~3;
    for (int e = 0; e < ne4; e += 4) {
      uint2 v[4]; h2 w2[4];
      #pragma unroll
      for (int u = 0; u < 4; ++u) {
        int sidx = __builtin_amdgcn_readlane(src_i, e + u);
        unsigned pku = (unsigned)__builtin_amdgcn_readlane((int)pk, e + u);
        unsigned wsp = (H == 2) ? __builtin_amdgcn_perm(pku, pku, psel) : pku;
        w2[u] = __builtin_bit_cast(h2, wsp);
        v[u] = *(const uint2*)&hin[(size_t)sidx * 256 + lane * 4];
      }
      #pragma unroll
      for (int u = 0; u < 4; ++u) {
        acc0 = __builtin_bit_cast(h2, v[u].x) * w2[u] + acc0;
        acc1 = __builtin_bit_cast(h2, v[u].y) * w2[u] + acc1;
      }
    }
  }

  float sh = (H == 2 && head) ? s1 : s0;
  float inv = 1.0f / sh;
  float4 bv = *(const float4*)&bias[lane * 4];
  float o0 = (float)acc0.x * inv + bv.x;
  float o1 = (float)acc0.y * inv + bv.y;
  float o2 = (float)acc1.x * inv + bv.z;
  float o3 = (float)acc1.y * inv + bv.w;
  if (OUT_LRELU) {
    o0 = lrelu(o0, 0.01f); o1 = lrelu(o1, 0.01f);
    o2 = lrelu(o2, 0.01f); o3 = lrelu(o3, 0.01f);
  }
  ushort4 o;
  o.x = f2h(o0); o.y = f2h(o1); o.z = f2h(o2); o.w = f2h(o3);
  *(ushort4*)&outp[(size_t)n * 256 + lane * 4] = o;
}

// ======================== launch ========================
extern "C" void kernel_launch(void* const* d_in, const int* in_sizes, int n_in,
                              void* d_out, int out_size, void* d_ws, size_t ws_size,
                              hipStream_t stream) {
  const float* x      = (const float*)d_in[0];
  const int*   ei     = (const int*)  d_in[1];
  const float* W1     = (const float*)d_in[2];
  const float* a_src1 = (const float*)d_in[3];
  const float* a_dst1 = (const float*)d_in[4];
  const float* b1     = (const float*)d_in[5];
  const float* W2     = (const float*)d_in[6];
  const float* a_src2 = (const float*)d_in[7];
  const float* a_dst2 = (const float*)d_in[8];
  const float* b2     = (const float*)d_in[9];
  const float* g      = (const float*)d_in[10];
  const float* mu     = (const float*)d_in[11];

  const int N  = in_sizes[0] / 256;            // 50000
  const int E  = in_sizes[1] / 2;              // 800000
  const int Mp = ((N + 127) / 128) * 128;      // 50048
  const int nb = (N + 255) / 256;              // 196 scan blocks
  const int* src = ei;
  const int* dst = ei + E;

  // ---- workspace layout ----
  unsigned short* us = (unsigned short*)d_ws;
  size_t off = 0;
  unsigned short* xb  = us + off; off += (size_t)Mp * 256;
  unsigned short* h1b = us + off; off += (size_t)Mp * 256;
  unsigned short* o1b = us + off; off += (size_t)Mp * 256;
  unsigned short* h2b = us + off; off += (size_t)Mp * 256;
  unsigned short* o2b = xb;                                  // alias
  float* f = (float*)(us + off);
  size_t fo = 0;
  float* asrc1 = f + fo; fo += (size_t)N * 2;
  float* adst1 = f + fo; fo += (size_t)N * 2;
  float* asrc2 = f + fo; fo += N;
  float* adst2 = f + fo; fo += N;
  float* nmu   = f + fo; fo += 8;
  int* deg    = (int*)(f + fo);
  int* rowptr = deg + N;
  int* cursor = rowptr + N + 1;
  int* colsrc = cursor + N;
  int* bsum   = colsrc + E;
  int* boff   = bsum + 256;
  unsigned short* w1b = (unsigned short*)(boff + 256);
  unsigned short* w2b = w1b + 256 * 256;
  unsigned short* gTb = w2b + 256 * 256;

  // ---- CSR build ----
  hipMemsetAsync(deg, 0, (size_t)N * sizeof(int), stream);
  hipMemsetAsync(asrc2, 0, (size_t)N * 2 * sizeof(float), stream);
  deg_kernel<<<(E + 255) / 256, 256, 0, stream>>>(dst, deg, E);
  bsum_kernel<<<nb, 256, 0, stream>>>(deg, bsum, N);
  bscan_kernel<<<1, 256, 0, stream>>>(bsum, boff, nb, rowptr + N);
  bwrite_kernel<<<nb, 256, 0, stream>>>(deg, boff, rowptr, cursor, N);
  fill_kernel<<<(E + 255) / 256, 256, 0, stream>>>(src, dst, cursor, colsrc, E);

  // ---- conversions ----
  cvt_rows_kernel<<<Mp / 4, 256, 0, stream>>>(x, xb, N, Mp);
  wsetup_kernel<<<1153, 256, 0, stream>>>(W1, W2, g, mu, w1b, w2b, gTb, nmu);

  const int gm = Mp / 128;   // 391

  // ---- layer 1 (alpha fused: nt == head) ----
  gemm_f16<0, 2, 2><<<gm, 256, 0, stream>>>(xb, w1b, h1b,
      a_src1, a_dst1, asrc1, adst1, nullptr, nullptr, nullptr, N);
  agg_kernel<2, true><<<(N + 3) / 4, 256, 0, stream>>>(h1b, asrc1, adst1, rowptr, colsrc, b1, o1b, N);

  // ---- layer 2 (alpha partials via atomicAdd) ----
  gemm_f16<0, 1, 2><<<gm, 256, 0, stream>>>(o1b, w2b, h2b,
      a_src2, a_dst2, asrc2, adst2, nullptr, nullptr, nullptr, N);
  agg_kernel<1, false><<<(N + 3) / 4, 256, 0, stream>>>(h2b, asrc2, adst2, rowptr, colsrc, b2, o2b, N);

  // ---- projection + fused cosine (nt == kchunk) ----
  gemm_f16<1, 0, 8><<<gm, 256, 0, stream>>>(o2b, gTb, nullptr,
      nullptr, nullptr, nullptr, nullptr, mu, nmu, (float*)d_out, N);
}